// Round 2
// baseline (110.591 us; speedup 1.0000x reference)
//
#include <hip/hip_runtime.h>
#include <math.h>

// ---------------------------------------------------------------------------
// QuantumClassifier_v2, fully fused: ONE kernel, one block per batch row.
// Per block (256 threads), all in LDS/registers:
//   h[b] = (x[b] @ W_down + b_down)/pi
//   WL1,WR1,WLF,WRF Clements interferometers (built redundantly per block,
//     4 in parallel across thread-groups of 50)
//   U1 = WR1 diag(e^{ih}) WL1
//   e1 = |perm5(U1[rows_nb, in_modes])|^2            (252, in LDS)
//   phi2[m] = sum_i e1[i*10+m]
//   UF = WRF diag(e^{i phi2}) WLF
//   out[b] = sum_k |perm5(UF[rows_b[k]])|^2/norm_k * W_out[k] + b_out
// No global intermediates; d_ws unused.
// ---------------------------------------------------------------------------

#define PI_F 3.14159265358979323846f

// C(n,k) for n<=13, k<=4 (lexicographic combination unranking)
__constant__ int BINOM[14][5] = {
  {1, 0, 0, 0, 0},  {1, 1, 0, 0, 0},  {1, 2, 1, 0, 0},   {1, 3, 3, 1, 0},
  {1, 4, 6, 4, 1},  {1, 5,10,10, 5},  {1, 6,15,20,15},   {1, 7,21,35,35},
  {1, 8,28,56,70},  {1, 9,36,84,126}, {1,10,45,120,210}, {1,11,55,165,330},
  {1,12,66,220,495},{1,13,78,286,715}
};
__constant__ float FACTF[6] = {1.f, 1.f, 2.f, 6.f, 24.f, 120.f};

__device__ __forceinline__ float2 cmul(float2 a, float2 b) {
  return make_float2(fmaf(a.x, b.x, -a.y * b.y), fmaf(a.x, b.y, a.y * b.x));
}
__device__ __forceinline__ float2 cadd(float2 a, float2 b) {
  return make_float2(a.x + b.x, a.y + b.y);
}
__device__ __forceinline__ float2 cscale(float2 a, float s) {
  return make_float2(a.x * s, a.y * s);
}
__device__ __forceinline__ float2 imul(float2 a) {  // i*a
  return make_float2(-a.y, a.x);
}

template <int N>
__device__ __forceinline__ void unrank5(int r, int c[5]) {
  int x = 0;
#pragma unroll
  for (int i = 0; i < 5; i++) {
    for (;;) {
      int cnt = BINOM[N - 1 - x][4 - i];
      if (r < cnt) { c[i] = x; x++; break; }
      r -= cnt; x++;
    }
  }
}

// Glynn permanent of 5x5 complex, Gray-code, fully unrolled (result = sum/16).
__device__ __forceinline__ float2 perm5(const float2 M[5][5]) {
  float2 rs[5];
#pragma unroll
  for (int j = 0; j < 5; j++) {
    rs[j] = M[0][j];
#pragma unroll
    for (int i = 1; i < 5; i++) rs[j] = cadd(rs[j], M[i][j]);
  }
  float2 acc = cmul(cmul(cmul(cmul(rs[0], rs[1]), rs[2]), rs[3]), rs[4]);
#pragma unroll
  for (int t = 1; t < 16; t++) {
    const int g = t ^ (t >> 1);
    const int bit = (t & 1) ? 0 : ((t & 2) ? 1 : ((t & 4) ? 2 : 3));  // ctz(t)
    const int i = bit + 1;
    const float step = ((g >> bit) & 1) ? -2.0f : 2.0f;
#pragma unroll
    for (int j = 0; j < 5; j++) {
      rs[j].x = fmaf(step, M[i][j].x, rs[j].x);
      rs[j].y = fmaf(step, M[i][j].y, rs[j].y);
    }
    float2 p = cmul(cmul(cmul(cmul(rs[0], rs[1]), rs[2]), rs[3]), rs[4]);
    const float s = (__popc(g) & 1) ? -1.0f : 1.0f;
    acc.x = fmaf(s, p.x, acc.x);
    acc.y = fmaf(s, p.y, acc.y);
  }
  return make_float2(acc.x * (1.0f / 16.0f), acc.y * (1.0f / 16.0f));
}

__global__ __launch_bounds__(256) void k_fused(
    const float* __restrict__ x, const float* __restrict__ Wd,
    const float* __restrict__ bd, const float* __restrict__ ph_l1,
    const float* __restrict__ ph_r1, const float* __restrict__ ph_lf,
    const float* __restrict__ ph_rf, const float* __restrict__ Wout,
    const float* __restrict__ bout, float* __restrict__ out) {
  const int b = blockIdx.x, tid = threadIdx.x;

  __shared__ float2 T[4][45][4];   // MZI 2x2 blocks, 4 interferometers
  __shared__ float2 Ui[4][100];    // 0=WL1, 1=WR1, 2=WLF, 3=WRF
  __shared__ float2 A[100];        // buildU temp
  __shared__ float2 Ub[100];       // U1 then UF
  __shared__ float  e1s[252];
  __shared__ float  red[4][10];
  __shared__ float2 v[10];

  // ---- head GEMV accumulation (registers only; reduce later) ----
  float hacc[10];
#pragma unroll
  for (int c = 0; c < 10; c++) hacc[c] = 0.f;
  for (int i = tid; i < 784; i += 256) {
    float xv = x[b * 784 + i];
    const float* w = Wd + i * 10;
#pragma unroll
    for (int c = 0; c < 10; c++) hacc[c] = fmaf(xv, w[c], hacc[c]);
  }

  // ---- MZI T-blocks for all 4 interferometers (180 entries) ----
  if (tid < 180) {
    const int which = tid / 45, m = tid % 45;
    const float* ph = (which == 0) ? ph_l1
                    : (which == 1) ? ph_r1
                    : (which == 2) ? ph_lf : ph_rf;
    float t1 = ph[m * 2 + 0], t2 = ph[m * 2 + 1];
    float s1, c1, s2, c2;
    sincosf(t1, &s1, &c1);
    sincosf(t2, &s2, &c2);
    float2 e2  = make_float2(c2, s2);
    float2 e1m = make_float2(c1 - 1.f, s1);   // e^{it1} - 1
    float2 e1p = make_float2(c1 + 1.f, s1);   // e^{it1} + 1
    T[which][m][0] = cscale(cmul(e2, e1m), 0.5f);
    T[which][m][1] = cscale(cmul(e2, imul(e1p)), 0.5f);
    T[which][m][2] = cscale(imul(e1p), 0.5f);
    T[which][m][3] = make_float2(0.5f * (1.f - c1), -0.5f * s1);
  }
  // identity init of the 4 U matrices
  for (int idx = tid; idx < 400; idx += 256)
    Ui[idx / 100][idx % 100] = make_float2((idx % 100) % 11 == 0 ? 1.f : 0.f, 0.f);

  // ---- head reduction into LDS ----
  {
    const int lane = tid & 63, wave = tid >> 6;
#pragma unroll
    for (int c = 0; c < 10; c++) {
      float r = hacc[c];
#pragma unroll
      for (int d = 32; d > 0; d >>= 1) r += __shfl_down(r, d);
      if (lane == 0) red[wave][c] = r;
    }
  }

  // ---- Clements layer sweep, 4 interferometers in parallel (groups of 50) ----
  int kb = 0;
  for (int layer = 0; layer < 10; layer++) {
    __syncthreads();
    const int start = layer & 1;
    const int npairs = 5 - start;
    if (tid < 200) {
      const int which = tid / 50, tl = tid % 50;
      if (tl < npairs * 10) {
        const int pi = tl / 10, n = tl % 10;
        const int p = start + 2 * pi;
        const int k = kb + pi;
        float2 u0 = Ui[which][p * 10 + n], u1 = Ui[which][(p + 1) * 10 + n];
        float2 n0 = cadd(cmul(T[which][k][0], u0), cmul(T[which][k][1], u1));
        float2 n1 = cadd(cmul(T[which][k][2], u0), cmul(T[which][k][3], u1));
        Ui[which][p * 10 + n] = n0;
        Ui[which][(p + 1) * 10 + n] = n1;
      }
    }
    kb += npairs;
  }
  __syncthreads();

  // ---- v = e^{i h[b]} ----
  if (tid < 10) {
    float s = red[0][tid] + red[1][tid] + red[2][tid] + red[3][tid] + bd[tid];
    s *= (1.0f / PI_F);
    float sn, cs;
    sincosf(s, &sn, &cs);
    v[tid] = make_float2(cs, sn);
  }
  __syncthreads();

  // ---- U1 = WR1 diag(v) WL1 ----
  if (tid < 100) A[tid] = cmul(Ui[1][tid], v[tid % 10]);
  __syncthreads();
  if (tid < 100) {
    const int m = tid / 10, n = tid % 10;
    float2 acc = make_float2(0.f, 0.f);
#pragma unroll
    for (int k = 0; k < 10; k++)
      acc = cadd(acc, cmul(A[m * 10 + k], Ui[0][k * 10 + n]));
    Ub[tid] = acc;
  }
  __syncthreads();

  // ---- e1: 252 no-bunching permanents ----
  if (tid < 252) {
    int c[5];
    unrank5<10>(tid, c);
    float2 M[5][5];
#pragma unroll
    for (int i = 0; i < 5; i++)
#pragma unroll
      for (int j = 0; j < 5; j++) M[i][j] = Ub[c[i] * 10 + 2 * j];
    float2 p = perm5(M);
    e1s[tid] = p.x * p.x + p.y * p.y;
  }
  __syncthreads();

  // ---- phi2 fold + v = e^{i phi2} ----
  if (tid < 10) {
    float s = 0.f;
    for (int idx = tid; idx < 252; idx += 10) s += e1s[idx];
    float sn, cs;
    sincosf(s, &sn, &cs);
    v[tid] = make_float2(cs, sn);
  }
  __syncthreads();

  // ---- UF = WRF diag(v) WLF ----
  if (tid < 100) A[tid] = cmul(Ui[3][tid], v[tid % 10]);
  __syncthreads();
  if (tid < 100) {
    const int m = tid / 10, n = tid % 10;
    float2 acc = make_float2(0.f, 0.f);
#pragma unroll
    for (int k = 0; k < 10; k++)
      acc = cadd(acc, cmul(A[m * 10 + k], Ui[2][k * 10 + n]));
    Ub[tid] = acc;
  }
  __syncthreads();

  // ---- 2002 bunched permanents, fused with probs @ W_out ----
  float acc[10];
#pragma unroll
  for (int c = 0; c < 10; c++) acc[c] = 0.f;
#pragma unroll
  for (int it = 0; it < 8; it++) {
    const int k = tid + it * 256;
    if (k < 2002) {
      int c5[5];
      unrank5<14>(k, c5);
      int modes[5];
#pragma unroll
      for (int i = 0; i < 5; i++) modes[i] = c5[i] - i;  // non-decreasing
      float2 M[5][5];
#pragma unroll
      for (int i = 0; i < 5; i++)
#pragma unroll
        for (int j = 0; j < 5; j++) M[i][j] = Ub[modes[i] * 10 + 2 * j];
      float2 p = perm5(M);
      float norm = 1.f;
      int run = 1;
#pragma unroll
      for (int i = 1; i < 5; i++) {
        if (modes[i] == modes[i - 1]) run++;
        else { norm *= FACTF[run]; run = 1; }
      }
      norm *= FACTF[run];
      const float pv = (p.x * p.x + p.y * p.y) / norm;
      const float* w = Wout + k * 10;
#pragma unroll
      for (int c = 0; c < 10; c++) acc[c] = fmaf(pv, w[c], acc[c]);
    }
  }

  // ---- final reduction + bias ----
  {
    const int lane = tid & 63, wave = tid >> 6;
#pragma unroll
    for (int c = 0; c < 10; c++) {
      float r = acc[c];
#pragma unroll
      for (int d = 32; d > 0; d >>= 1) r += __shfl_down(r, d);
      if (lane == 0) red[wave][c] = r;
    }
  }
  __syncthreads();
  if (tid < 10) {
    float s = red[0][tid] + red[1][tid] + red[2][tid] + red[3][tid];
    out[b * 10 + tid] = s + bout[tid];
  }
}

extern "C" void kernel_launch(void* const* d_in, const int* in_sizes, int n_in,
                              void* d_out, int out_size, void* d_ws,
                              size_t ws_size, hipStream_t stream) {
  const float* x    = (const float*)d_in[0];  // [128,784]
  const float* Wd   = (const float*)d_in[1];  // [784,10]
  const float* bd   = (const float*)d_in[2];  // [10]
  const float* pl1  = (const float*)d_in[3];  // [45,2]
  const float* pr1  = (const float*)d_in[4];  // [45,2]
  const float* plf  = (const float*)d_in[5];  // [45,2]
  const float* prf  = (const float*)d_in[6];  // [45,2]
  const float* Wout = (const float*)d_in[7];  // [2002,10]
  const float* bout = (const float*)d_in[8];  // [10]
  float* out = (float*)d_out;                 // [128,10]

  k_fused<<<128, 256, 0, stream>>>(x, Wd, bd, pl1, pr1, plf, prf, Wout, bout,
                                   out);
}

// Round 3
// 92.802 us; speedup vs baseline: 1.1917x; 1.1917x over previous
//
#include <hip/hip_runtime.h>
#include <math.h>

// ---------------------------------------------------------------------------
// QuantumClassifier_v2 on MI355X, two kernels:
//  k_prefix (128 blocks): h -> interferometers -> U1 -> e1 (252 perms) ->
//     phi2 -> UF; stores UF[b] to ws, seeds out[b] = b_out.
//  k_perms (1024 blocks, 8/row): one bunched permanent per thread (2002/row),
//     fused with W_out; block-reduce + atomicAdd into out.
// Combination unranking is a register-only binomial walk (exact fp32 math:
// C(m-1,j) = C(m,j)(m-j)/m, C(m-1,j-1) = C(m,j) j/m; values < 2^14).
// ---------------------------------------------------------------------------

#define PI_F 3.14159265358979323846f

__constant__ float FACTF[6] = {1.f, 1.f, 2.f, 6.f, 24.f, 120.f};

__device__ __forceinline__ float2 cmul(float2 a, float2 b) {
  return make_float2(fmaf(a.x, b.x, -a.y * b.y), fmaf(a.x, b.y, a.y * b.x));
}
__device__ __forceinline__ float2 cadd(float2 a, float2 b) {
  return make_float2(a.x + b.x, a.y + b.y);
}
__device__ __forceinline__ float2 cscale(float2 a, float s) {
  return make_float2(a.x * s, a.y * s);
}
__device__ __forceinline__ float2 imul(float2 a) {  // i*a
  return make_float2(-a.y, a.x);
}

// Register-only lexicographic unranking of 5-combinations of {0..N-1}.
// cnt0 = C(N-1,4), m0 = N-1. All intermediates are exact integers in fp32.
__device__ __forceinline__ void unrank5f(int rank, float cnt0, float m0,
                                         int c[5]) {
  float r = (float)rank;
  float cnt = cnt0, m = m0, j = 4.f;
  int x = 0;
#pragma unroll
  for (int i = 0; i < 5; i++) {
    while (r >= cnt) {            // skip value x
      r -= cnt;
      cnt = cnt * (m - j) / m;    // C(m-1, j)
      m -= 1.f;
      x++;
    }
    c[i] = x;                     // take value x
    cnt = cnt * j / m;            // C(m-1, j-1)
    m -= 1.f;
    j -= 1.f;
    x++;
  }
}

// 5-way complex product, tree-shaped (depth 3 cmuls).
__device__ __forceinline__ float2 prod5(const float2 rs[5]) {
  return cmul(cmul(cmul(rs[0], rs[1]), cmul(rs[2], rs[3])), rs[4]);
}

// Glynn permanent of 5x5 complex, Gray-code, fully unrolled (result = sum/16).
__device__ __forceinline__ float2 perm5(const float2 M[5][5]) {
  float2 rs[5];
#pragma unroll
  for (int j = 0; j < 5; j++) {
    rs[j] = M[0][j];
#pragma unroll
    for (int i = 1; i < 5; i++) rs[j] = cadd(rs[j], M[i][j]);
  }
  float2 acc = prod5(rs);
#pragma unroll
  for (int t = 1; t < 16; t++) {
    const int g = t ^ (t >> 1);
    const int bit = (t & 1) ? 0 : ((t & 2) ? 1 : ((t & 4) ? 2 : 3));  // ctz(t)
    const int i = bit + 1;
    const float step = ((g >> bit) & 1) ? -2.0f : 2.0f;
#pragma unroll
    for (int j = 0; j < 5; j++) {
      rs[j].x = fmaf(step, M[i][j].x, rs[j].x);
      rs[j].y = fmaf(step, M[i][j].y, rs[j].y);
    }
    float2 p = prod5(rs);
    const float s = (__popc(g) & 1) ? -1.0f : 1.0f;
    acc.x = fmaf(s, p.x, acc.x);
    acc.y = fmaf(s, p.y, acc.y);
  }
  return make_float2(acc.x * (1.0f / 16.0f), acc.y * (1.0f / 16.0f));
}

// ---------------------------------------------------------------------------
// Kernel 1: everything through UF; one block per batch row.
// ---------------------------------------------------------------------------
__global__ __launch_bounds__(256) void k_prefix(
    const float* __restrict__ x, const float* __restrict__ Wd,
    const float* __restrict__ bd, const float* __restrict__ ph_l1,
    const float* __restrict__ ph_r1, const float* __restrict__ ph_lf,
    const float* __restrict__ ph_rf, const float* __restrict__ bout,
    float2* __restrict__ UFws, float* __restrict__ out) {
  const int b = blockIdx.x, tid = threadIdx.x;

  __shared__ float2 T[4][45][4];
  __shared__ float2 Ui[4][100];  // 0=WL1, 1=WR1, 2=WLF, 3=WRF
  __shared__ float2 A[100];
  __shared__ float2 Ub[100];
  __shared__ float  e1s[252];
  __shared__ float  red[4][10];
  __shared__ float2 v[10];

  // head GEMV accumulation (registers)
  float hacc[10];
#pragma unroll
  for (int c = 0; c < 10; c++) hacc[c] = 0.f;
  for (int i = tid; i < 784; i += 256) {
    float xv = x[b * 784 + i];
    const float* w = Wd + i * 10;
#pragma unroll
    for (int c = 0; c < 10; c++) hacc[c] = fmaf(xv, w[c], hacc[c]);
  }

  // MZI 2x2 blocks for all 4 interferometers
  if (tid < 180) {
    const int which = tid / 45, m = tid % 45;
    const float* ph = (which == 0) ? ph_l1
                    : (which == 1) ? ph_r1
                    : (which == 2) ? ph_lf : ph_rf;
    float t1 = ph[m * 2 + 0], t2 = ph[m * 2 + 1];
    float s1, c1, s2, c2;
    sincosf(t1, &s1, &c1);
    sincosf(t2, &s2, &c2);
    float2 e2  = make_float2(c2, s2);
    float2 e1m = make_float2(c1 - 1.f, s1);
    float2 e1p = make_float2(c1 + 1.f, s1);
    T[which][m][0] = cscale(cmul(e2, e1m), 0.5f);
    T[which][m][1] = cscale(cmul(e2, imul(e1p)), 0.5f);
    T[which][m][2] = cscale(imul(e1p), 0.5f);
    T[which][m][3] = make_float2(0.5f * (1.f - c1), -0.5f * s1);
  }
  for (int idx = tid; idx < 400; idx += 256)
    Ui[idx / 100][idx % 100] =
        make_float2((idx % 100) % 11 == 0 ? 1.f : 0.f, 0.f);

  // head reduction into LDS
  {
    const int lane = tid & 63, wave = tid >> 6;
#pragma unroll
    for (int c = 0; c < 10; c++) {
      float r = hacc[c];
#pragma unroll
      for (int d = 32; d > 0; d >>= 1) r += __shfl_down(r, d);
      if (lane == 0) red[wave][c] = r;
    }
  }

  // Clements layer sweep, 4 interferometers in parallel
  int kb = 0;
  for (int layer = 0; layer < 10; layer++) {
    __syncthreads();
    const int start = layer & 1;
    const int npairs = 5 - start;
    if (tid < 200) {
      const int which = tid / 50, tl = tid % 50;
      if (tl < npairs * 10) {
        const int pi = tl / 10, n = tl % 10;
        const int p = start + 2 * pi;
        const int k = kb + pi;
        float2 u0 = Ui[which][p * 10 + n], u1 = Ui[which][(p + 1) * 10 + n];
        float2 n0 = cadd(cmul(T[which][k][0], u0), cmul(T[which][k][1], u1));
        float2 n1 = cadd(cmul(T[which][k][2], u0), cmul(T[which][k][3], u1));
        Ui[which][p * 10 + n] = n0;
        Ui[which][(p + 1) * 10 + n] = n1;
      }
    }
    kb += npairs;
  }
  __syncthreads();

  if (tid < 10) {
    float s = red[0][tid] + red[1][tid] + red[2][tid] + red[3][tid] + bd[tid];
    s *= (1.0f / PI_F);
    float sn, cs;
    sincosf(s, &sn, &cs);
    v[tid] = make_float2(cs, sn);
  }
  __syncthreads();

  // U1 = WR1 diag(v) WL1
  if (tid < 100) A[tid] = cmul(Ui[1][tid], v[tid % 10]);
  __syncthreads();
  if (tid < 100) {
    const int m = tid / 10, n = tid % 10;
    float2 acc = make_float2(0.f, 0.f);
#pragma unroll
    for (int k = 0; k < 10; k++)
      acc = cadd(acc, cmul(A[m * 10 + k], Ui[0][k * 10 + n]));
    Ub[tid] = acc;
  }
  __syncthreads();

  // e1: 252 no-bunching permanents (one per thread)
  if (tid < 252) {
    int c[5];
    unrank5f(tid, 126.f, 9.f, c);  // C(9,4)=126, N-1=9
    float2 M[5][5];
#pragma unroll
    for (int i = 0; i < 5; i++)
#pragma unroll
      for (int j = 0; j < 5; j++) M[i][j] = Ub[c[i] * 10 + 2 * j];
    float2 p = perm5(M);
    e1s[tid] = p.x * p.x + p.y * p.y;
  }
  __syncthreads();

  // phi2 fold + v = e^{i phi2}
  if (tid < 10) {
    float s = 0.f;
    for (int idx = tid; idx < 252; idx += 10) s += e1s[idx];
    float sn, cs;
    sincosf(s, &sn, &cs);
    v[tid] = make_float2(cs, sn);
  }
  __syncthreads();

  // UF = WRF diag(v) WLF
  if (tid < 100) A[tid] = cmul(Ui[3][tid], v[tid % 10]);
  __syncthreads();
  if (tid < 100) {
    const int m = tid / 10, n = tid % 10;
    float2 acc = make_float2(0.f, 0.f);
#pragma unroll
    for (int k = 0; k < 10; k++)
      acc = cadd(acc, cmul(A[m * 10 + k], Ui[2][k * 10 + n]));
    UFws[b * 100 + tid] = acc;
  }
  // seed output with bias (kernel 2 atomically accumulates on top)
  if (tid < 10) out[b * 10 + tid] = bout[tid];
}

// ---------------------------------------------------------------------------
// Kernel 2: 8 blocks per batch row; one bunched permanent per thread.
// ---------------------------------------------------------------------------
__global__ __launch_bounds__(256) void k_perms(const float2* __restrict__ UFws,
                                               const float* __restrict__ Wout,
                                               float* __restrict__ out) {
  const int b = blockIdx.x >> 3, chunk = blockIdx.x & 7;
  const int tid = threadIdx.x;
  const int k = chunk * 256 + tid;
  __shared__ float2 U[100];
  __shared__ float red[4][10];
  if (tid < 100) U[tid] = UFws[b * 100 + tid];
  __syncthreads();

  float acc[10];
#pragma unroll
  for (int c = 0; c < 10; c++) acc[c] = 0.f;

  if (k < 2002) {
    int c5[5];
    unrank5f(k, 715.f, 13.f, c5);  // C(13,4)=715, N-1=13
    int modes[5];
#pragma unroll
    for (int i = 0; i < 5; i++) modes[i] = c5[i] - i;  // non-decreasing
    float2 M[5][5];
#pragma unroll
    for (int i = 0; i < 5; i++)
#pragma unroll
      for (int j = 0; j < 5; j++) M[i][j] = U[modes[i] * 10 + 2 * j];
    float2 p = perm5(M);
    float norm = 1.f;
    int run = 1;
#pragma unroll
    for (int i = 1; i < 5; i++) {
      if (modes[i] == modes[i - 1]) run++;
      else { norm *= FACTF[run]; run = 1; }
    }
    norm *= FACTF[run];
    const float pv = (p.x * p.x + p.y * p.y) / norm;
    const float2* w2 = (const float2*)Wout + k * 5;  // row k (40B, 8B-aligned)
#pragma unroll
    for (int c = 0; c < 5; c++) {
      float2 w = w2[c];
      acc[2 * c + 0] = pv * w.x;
      acc[2 * c + 1] = pv * w.y;
    }
  }

  const int lane = tid & 63, wave = tid >> 6;
#pragma unroll
  for (int c = 0; c < 10; c++) {
    float r = acc[c];
#pragma unroll
    for (int d = 32; d > 0; d >>= 1) r += __shfl_down(r, d);
    if (lane == 0) red[wave][c] = r;
  }
  __syncthreads();
  if (tid < 10) {
    float s = red[0][tid] + red[1][tid] + red[2][tid] + red[3][tid];
    atomicAdd(&out[b * 10 + tid], s);
  }
}

extern "C" void kernel_launch(void* const* d_in, const int* in_sizes, int n_in,
                              void* d_out, int out_size, void* d_ws,
                              size_t ws_size, hipStream_t stream) {
  const float* x    = (const float*)d_in[0];  // [128,784]
  const float* Wd   = (const float*)d_in[1];  // [784,10]
  const float* bd   = (const float*)d_in[2];  // [10]
  const float* pl1  = (const float*)d_in[3];  // [45,2]
  const float* pr1  = (const float*)d_in[4];  // [45,2]
  const float* plf  = (const float*)d_in[5];  // [45,2]
  const float* prf  = (const float*)d_in[6];  // [45,2]
  const float* Wout = (const float*)d_in[7];  // [2002,10]
  const float* bout = (const float*)d_in[8];  // [10]
  float* out = (float*)d_out;                 // [128,10]

  float2* UFws = (float2*)d_ws;  // 128*100 complex64 = 100 KiB

  k_prefix<<<128, 256, 0, stream>>>(x, Wd, bd, pl1, pr1, plf, prf, bout, UFws,
                                    out);
  k_perms<<<1024, 256, 0, stream>>>(UFws, Wout, out);
}